// Round 7
// baseline (347.484 us; speedup 1.0000x reference)
//
#include <hip/hip_runtime.h>
#include <math.h>

#define NBINS 28
#define L2E 1.44269504088896340736f

#define EXP2F(x) __builtin_amdgcn_exp2f(x)
#define RCPF(x)  __builtin_amdgcn_rcpf(x)
#define SCHED_FENCE() __builtin_amdgcn_sched_barrier(0)

// LDS/workspace float offsets.
// WS_WFLAT: all of W1+W2 as 96 float4s in EXACT consumption order, 24 chunks
// of 4 float4 each (so the k-loop pipeline loads chunk c as sw[4c..4c+3]):
//   chunks 0..7  : layer1, quad q = c>>1, f = (c&1)*4 + i   (prescaled -log2e)
//   chunks 8..23 : layer2, quad q = (c-8)>>2, k = ((c-8)&3)*4 + i  (-log2e)
#define WS_TBL   0     // 40 floats: ml_table[d-1], d=1..40
#define WS_WFLAT 64    // 384 floats (96 float4, chunk-ordered)
#define WS_B1    448   // 16, prescaled -log2e
#define WS_B2    464   // 16, prescaled -log2e
#define WS_W3    480   // 16, prescaled +log2e
#define WS_B3    496   // 1,  prescaled +log2e
#define WS_TOT   512

__global__ void prep_kernel(const float* __restrict__ mh_W1, const float* __restrict__ mh_b1,
                            const float* __restrict__ mh_W2, const float* __restrict__ mh_b2,
                            const float* __restrict__ mh_W3, const float* __restrict__ mh_b3,
                            const float* __restrict__ ml_W1, const float* __restrict__ ml_b1,
                            const float* __restrict__ ml_W2, const float* __restrict__ ml_b2,
                            const float* __restrict__ ml_W3, const float* __restrict__ ml_b3,
                            float* __restrict__ ws, float* __restrict__ out_bins) {
    const int t = threadIdx.x;  // 64 threads
    // chunk-ordered W1+W2 (see layout comment above)
    for (int idx = t; idx < 384; idx += 64) {
        const int e  = idx >> 2;   // float4 index 0..95
        const int cc = idx & 3;    // component
        const int c  = e >> 2;     // chunk 0..23
        const int i  = e & 3;      // slot in chunk
        float val;
        if (c < 8) {
            const int q = c >> 1, f = ((c & 1) << 2) + i;
            val = -L2E * mh_W1[f * 16 + q * 4 + cc];
        } else {
            const int c2 = c - 8;
            const int q = c2 >> 2, k = ((c2 & 3) << 2) + i;
            val = -L2E * mh_W2[k * 16 + q * 4 + cc];
        }
        ws[WS_WFLAT + idx] = val;
    }
    for (int k = t; k < 16; k += 64) ws[WS_B1 + k] = -L2E * mh_b1[k];
    for (int k = t; k < 16; k += 64) ws[WS_B2 + k] = -L2E * mh_b2[k];
    for (int k = t; k < 16; k += 64) ws[WS_W3 + k] =  L2E * mh_W3[k];
    if (t == 0) ws[WS_B3] = L2E * mh_b3[0];

    if (t < 40) {
        const float x = (float)(t + 1);
        float h1[16], h2[16];
        #pragma unroll
        for (int j = 0; j < 16; ++j)
            h1[j] = 1.0f / (1.0f + expf(-(x * ml_W1[j] + ml_b1[j])));
        #pragma unroll
        for (int j = 0; j < 16; ++j) {
            float a = ml_b2[j];
            #pragma unroll
            for (int k = 0; k < 16; ++k) a = fmaf(h1[k], ml_W2[k * 16 + j], a);
            h2[j] = 1.0f / (1.0f + expf(-a));
        }
        float phi = ml_b3[0];
        #pragma unroll
        for (int k = 0; k < 16; ++k) phi = fmaf(h2[k], ml_W3[k], phi);
        const float sc = expf(phi - 0.25f * x);
        ws[WS_TBL + t] = sc;
        if (t < NBINS) out_bins[t] = sc;  // dl2_scores term of output 1
    }
}

// 2 rows/thread, one-shot, UNCAPPED (R2/R3/R5: any VGPR cap -> GB-scale
// spills; R4/R6 uncapped -> clean).  NEW in R7: software-pipelined weight
// loads.  Each sched_barrier region = [issue ds_reads for chunk c+1 into the
// other buffer; FMAs for chunk c].  Compiler then waits with lgkmcnt(4/5)
// (next chunk stays in flight) instead of the R6 pattern [load; drain; FMA]
// which exposed full ds_read latency every 4 loads and left the DS pipe at
// ~38% utilization (173 us vs the 66 us DS floor at 2 rows/thread).
__global__ __launch_bounds__(256) void main_kernel(
        const float4* __restrict__ x4,
        const int2* __restrict__ dl2p,
        const int2* __restrict__ ml2p,
        const float* __restrict__ ws,
        float2* __restrict__ out2,
        float* __restrict__ out_bins,
        int npair) {
    __shared__ float s[WS_TOT];
    __shared__ float s_bins[4 * NBINS];
    const int tid = threadIdx.x;
    #pragma unroll
    for (int k = tid; k < WS_TOT; k += 256) s[k] = ws[k];
    if (tid < 4 * NBINS) s_bins[tid] = 0.0f;
    __syncthreads();

    const float4* sw    = (const float4*)&s[WS_WFLAT];  // 96 float4, chunk-ordered
    const float4* sB1f4 = (const float4*)&s[WS_B1];
    const float4* sB2f4 = (const float4*)&s[WS_B2];
    const float4* sW3f4 = (const float4*)&s[WS_W3];

    const int p = blockIdx.x * 256 + tid;
    const bool active = (p < npair);
    const int pc = active ? p : 0;

    const float4 a0 = x4[4 * pc + 0];
    const float4 a1 = x4[4 * pc + 1];
    const float4 b0 = x4[4 * pc + 2];
    const float4 b1 = x4[4 * pc + 3];
    const int2 dl = dl2p[pc];
    const int2 ml = ml2p[pc];
    const float xf0[8] = {a0.x, a0.y, a0.z, a0.w, a1.x, a1.y, a1.z, a1.w};
    const float xf1[8] = {b0.x, b0.y, b0.z, b0.w, b1.x, b1.y, b1.z, b1.w};

    float4 A[4], B[4];
    auto loadA = [&](int c) { const int cc = (c < 24) ? c : 0;
        A[0] = sw[4*cc+0]; A[1] = sw[4*cc+1]; A[2] = sw[4*cc+2]; A[3] = sw[4*cc+3]; };
    auto loadB = [&](int c) { const int cc = (c < 24) ? c : 0;
        B[0] = sw[4*cc+0]; B[1] = sw[4*cc+1]; B[2] = sw[4*cc+2]; B[3] = sw[4*cc+3]; };
    // chunk FMA: acc += src[base+i] * W[i]  (4 float4 weights, 2 rows)
    auto fma_first = [&](const float4* W, float4& c0r, float4& c1r,
                         const float* s0, const float* s1, int base) {
        { const float4 w = W[0]; const float x0 = s0[base], x1 = s1[base];
          c0r.x = x0*w.x; c0r.y = x0*w.y; c0r.z = x0*w.z; c0r.w = x0*w.w;
          c1r.x = x1*w.x; c1r.y = x1*w.y; c1r.z = x1*w.z; c1r.w = x1*w.w; }
        #pragma unroll
        for (int i = 1; i < 4; ++i) {
            const float4 w = W[i]; const float x0 = s0[base+i], x1 = s1[base+i];
            c0r.x = fmaf(x0, w.x, c0r.x); c0r.y = fmaf(x0, w.y, c0r.y);
            c0r.z = fmaf(x0, w.z, c0r.z); c0r.w = fmaf(x0, w.w, c0r.w);
            c1r.x = fmaf(x1, w.x, c1r.x); c1r.y = fmaf(x1, w.y, c1r.y);
            c1r.z = fmaf(x1, w.z, c1r.z); c1r.w = fmaf(x1, w.w, c1r.w);
        }
    };
    auto fma_next = [&](const float4* W, float4& c0r, float4& c1r,
                        const float* s0, const float* s1, int base) {
        #pragma unroll
        for (int i = 0; i < 4; ++i) {
            const float4 w = W[i]; const float x0 = s0[base+i], x1 = s1[base+i];
            c0r.x = fmaf(x0, w.x, c0r.x); c0r.y = fmaf(x0, w.y, c0r.y);
            c0r.z = fmaf(x0, w.z, c0r.z); c0r.w = fmaf(x0, w.w, c0r.w);
            c1r.x = fmaf(x1, w.x, c1r.x); c1r.y = fmaf(x1, w.y, c1r.y);
            c1r.z = fmaf(x1, w.z, c1r.z); c1r.w = fmaf(x1, w.w, c1r.w);
        }
    };

    float h10[16], h11[16];
    float4 u0, u1;

    loadA(0);              // prologue: chunk 0
    SCHED_FENCE();

    // ---- layer 1: quads q=0..3, chunks 2q (A) and 2q+1 (B) ----
    #pragma unroll
    for (int q = 0; q < 4; ++q) {
        const int c0 = 2 * q;
        // region 1: prefetch chunk c0+1 (B) + this quad's bias; FMA chunk c0 (A)
        loadB(c0 + 1);
        const float4 b1q = sB1f4[q];
        fma_first(A, u0, u1, xf0, xf1, 0);
        SCHED_FENCE();
        // region 2: prefetch chunk c0+2 (A); FMA chunk c0+1 (B); sigmoids
        loadA(c0 + 2);
        fma_next(B, u0, u1, xf0, xf1, 4);
        h10[4*q+0] = RCPF(1.0f + EXP2F(u0.x + b1q.x));
        h10[4*q+1] = RCPF(1.0f + EXP2F(u0.y + b1q.y));
        h10[4*q+2] = RCPF(1.0f + EXP2F(u0.z + b1q.z));
        h10[4*q+3] = RCPF(1.0f + EXP2F(u0.w + b1q.w));
        h11[4*q+0] = RCPF(1.0f + EXP2F(u1.x + b1q.x));
        h11[4*q+1] = RCPF(1.0f + EXP2F(u1.y + b1q.y));
        h11[4*q+2] = RCPF(1.0f + EXP2F(u1.z + b1q.z));
        h11[4*q+3] = RCPF(1.0f + EXP2F(u1.w + b1q.w));
        SCHED_FENCE();
    }

    // ---- layer 2+3: quads q=0..3, chunks 8+4q .. 8+4q+3 ----
    float phi0 = 0.0f, phi1 = 0.0f;
    float4 v0, v1;
    #pragma unroll
    for (int q = 0; q < 4; ++q) {
        const int c0 = 8 + 4 * q;
        // region 1: prefetch c0+1 (B); FMA c0 (A), k=0..3
        loadB(c0 + 1);
        fma_first(A, v0, v1, h10, h11, 0);
        SCHED_FENCE();
        // region 2: prefetch c0+2 (A) + bias/W3 for this quad; FMA c0+1 (B), k=4..7
        loadA(c0 + 2);
        const float4 b2q = sB2f4[q];
        const float4 w3q = sW3f4[q];
        fma_next(B, v0, v1, h10, h11, 4);
        SCHED_FENCE();
        // region 3: prefetch c0+3 (B); FMA c0+2 (A), k=8..11
        loadB(c0 + 3);
        fma_next(A, v0, v1, h10, h11, 8);
        SCHED_FENCE();
        // region 4: prefetch c0+4 (A, wraps to 0 at end); FMA c0+3 (B), k=12..15;
        //           sigmoid + W3 dot
        loadA(c0 + 4);
        fma_next(B, v0, v1, h10, h11, 12);
        phi0 = fmaf(RCPF(1.0f + EXP2F(v0.x + b2q.x)), w3q.x, phi0);
        phi0 = fmaf(RCPF(1.0f + EXP2F(v0.y + b2q.y)), w3q.y, phi0);
        phi0 = fmaf(RCPF(1.0f + EXP2F(v0.z + b2q.z)), w3q.z, phi0);
        phi0 = fmaf(RCPF(1.0f + EXP2F(v0.w + b2q.w)), w3q.w, phi0);
        phi1 = fmaf(RCPF(1.0f + EXP2F(v1.x + b2q.x)), w3q.x, phi1);
        phi1 = fmaf(RCPF(1.0f + EXP2F(v1.y + b2q.y)), w3q.y, phi1);
        phi1 = fmaf(RCPF(1.0f + EXP2F(v1.z + b2q.z)), w3q.z, phi1);
        phi1 = fmaf(RCPF(1.0f + EXP2F(v1.w + b2q.w)), w3q.w, phi1);
        SCHED_FENCE();
    }

    const float b3 = s[WS_B3];
    const float sc0 = EXP2F(fmaf((float)dl.x, -0.25f * L2E, phi0 + b3));
    const float sc1 = EXP2F(fmaf((float)dl.y, -0.25f * L2E, phi1 + b3));

    // ---- epilogue ----
    if (active) {
        const int i0 = min(max(dl.x, 1), 40) - 1;
        const int i1 = min(max(dl.y, 1), 40) - 1;
        const float add0 = (dl.x == ml.x) ? s[WS_TBL + i0] : 0.0f;
        const float add1 = (dl.y == ml.y) ? s[WS_TBL + i1] : 0.0f;
        out2[p] = make_float2(sc0 + add0, sc1 + add1);
        float* myb = &s_bins[(tid >> 6) * NBINS];
        if (dl.x >= 1 && dl.x <= NBINS) unsafeAtomicAdd(&myb[dl.x - 1], sc0);
        if (dl.y >= 1 && dl.y <= NBINS) unsafeAtomicAdd(&myb[dl.y - 1], sc1);
    }

    __syncthreads();
    if (tid < NBINS) {
        const float bsum = s_bins[tid] + s_bins[NBINS + tid] +
                           s_bins[2 * NBINS + tid] + s_bins[3 * NBINS + tid];
        unsafeAtomicAdd(&out_bins[tid], bsum);
    }
}

extern "C" void kernel_launch(void* const* d_in, const int* in_sizes, int n_in,
                              void* d_out, int out_size, void* d_ws, size_t ws_size,
                              hipStream_t stream) {
    const int n = in_sizes[0] / 8;  // N rows (even)

    const float* x_feat = (const float*)d_in[0];
    const float* mh_W1  = (const float*)d_in[1];
    const float* mh_b1  = (const float*)d_in[2];
    const float* mh_W2  = (const float*)d_in[3];
    const float* mh_b2  = (const float*)d_in[4];
    const float* mh_W3  = (const float*)d_in[5];
    const float* mh_b3  = (const float*)d_in[6];
    const float* ml_W1  = (const float*)d_in[7];
    const float* ml_b1  = (const float*)d_in[8];
    const float* ml_W2  = (const float*)d_in[9];
    const float* ml_b2  = (const float*)d_in[10];
    const float* ml_W3  = (const float*)d_in[11];
    const float* ml_b3  = (const float*)d_in[12];
    const int* del_lens = (const int*)d_in[13];
    const int* mh_len   = (const int*)d_in[14];

    float* out      = (float*)d_out;
    float* out_bins = out + n;  // last 28 elements of d_out
    float* ws       = (float*)d_ws;

    prep_kernel<<<dim3(1), dim3(64), 0, stream>>>(
        mh_W1, mh_b1, mh_W2, mh_b2, mh_W3, mh_b3,
        ml_W1, ml_b1, ml_W2, ml_b2, ml_W3, ml_b3,
        ws, out_bins);

    const int npair = n / 2;
    const int nblocks = (npair + 255) / 256;
    main_kernel<<<dim3(nblocks), dim3(256), 0, stream>>>(
        (const float4*)x_feat, (const int2*)del_lens, (const int2*)mh_len,
        ws, (float2*)out, out_bins, npair);
}